// Round 20
// baseline (942.970 us; speedup 1.0000x reference)
//
#include <hip/hip_runtime.h>

#define NN 50000
#define NE 1200000
#define CCH 64
#define NLAYER 8
#define HID 128
#define NG 128
#define BN_EPS 1e-5f
#define SCAN_NB ((NN + 255) / 256)   // 196 buckets
#define EDGE_CHUNK 8192              // edges per bucket_scatter block
#define BCAP 8064                    // staging capacity per bucket (mean 6144, +24 sigma)

// ---- workspace layout (offsets in floats) ----
enum : size_t {
  OFF_STATS  = 0,
  OFF_POOLED = 1152,
  OFF_COUNTS = 9344,
  OFF_GCUR   = 9472,       // 196 bucket counters (ints)
  MEMSET_F   = 9728,
  OFF_DIS    = 9728,
  OFF_OFFS   = 59728,      // N+1 (+pad)
  OFF_CSRSRC = 109988,     // ushort[E]
  OFF_H      = 709988,     // ushort[N*64] bf16 (800000 floats)
  OFF_HW     = 2309988,    // ushort[4][N][16] bf16 slabs; staging (uint[196*BCAP]) aliases
  WS_FLOATS  = 3909988
};

__device__ __forceinline__ float bf2f(unsigned int hs) {
  union { unsigned int u; float f; } c; c.u = hs << 16; return c.f;
}
__device__ __forceinline__ unsigned int f2bf(float x) {
  union { float f; unsigned int u; } c; c.f = x;
  return (c.u + 0x7fffu + ((c.u >> 16) & 1u)) >> 16;  // RNE
}

// ---- CSR build phase A: bucket edges by dst>>8 into fixed-capacity staging.
__global__ __launch_bounds__(256) void bucket_scatter_kernel(const int* __restrict__ ei,
    int* __restrict__ gcur, unsigned int* __restrict__ staging) {
  __shared__ int bcnt[SCAN_NB];
  __shared__ int bbase[SCAN_NB];
  int tid = threadIdx.x;
  int lo = blockIdx.x * EDGE_CHUNK;
  int hi = lo + EDGE_CHUNK; if (hi > NE) hi = NE;
  for (int b = tid; b < SCAN_NB; b += 256) bcnt[b] = 0;
  __syncthreads();
  for (int e = lo + tid; e < hi; e += 256)
    atomicAdd(&bcnt[__builtin_nontemporal_load(&ei[NE + e]) >> 8], 1);
  __syncthreads();
  for (int b = tid; b < SCAN_NB; b += 256) {
    int c = bcnt[b];
    bbase[b] = c ? (b * BCAP + atomicAdd(&gcur[b], c)) : 0;
    bcnt[b] = 0;
  }
  __syncthreads();
  for (int e = lo + tid; e < hi; e += 256) {
    int src = __builtin_nontemporal_load(&ei[e]);
    int dst = ei[NE + e];
    int b = dst >> 8;
    int p = bbase[b] + atomicAdd(&bcnt[b], 1);
    __builtin_nontemporal_store(((unsigned int)(dst & 255) << 16) | (unsigned int)src,
                                &staging[p]);
  }
}

// ---- CSR build phase B (scan fused): per bucket — block computes its own
// prefix over gcur, then LDS degree histogram -> dis, LDS scan -> offs,
// LDS cursors -> csr_src placement.
__global__ __launch_bounds__(256) void bucket_build_kernel(const unsigned int* __restrict__ staging,
    const int* __restrict__ gcur,
    int* __restrict__ offs, float* __restrict__ dis, unsigned short* __restrict__ csr_src) {
  __shared__ int hcnt[256];
  __shared__ int sm[256];
  __shared__ int ncur[256];
  __shared__ int sm_base;
  int b = blockIdx.x;
  int tid = threadIdx.x;
  int cnt = gcur[b];
  if (tid < 64) {
    int s = 0;
    for (int j = tid; j < b; j += 64) s += gcur[j];
    for (int d = 1; d < 64; d <<= 1) s += __shfl_xor(s, d);
    if (tid == 0) sm_base = s;
  }
  const unsigned int* st = staging + (size_t)b * BCAP;
  hcnt[tid] = 0;
  __syncthreads();
  int base = sm_base;
  for (int e = tid; e < cnt; e += 256)
    atomicAdd(&hcnt[__builtin_nontemporal_load(&st[e]) >> 16], 1);
  __syncthreads();
  int d = hcnt[tid];
  int node = (b << 8) + tid;
  if (node < NN) dis[node] = rsqrtf((float)(d + 1));  // +1 self-loop
  sm[tid] = d;
  __syncthreads();
  for (int s = 1; s < 256; s <<= 1) {
    int add = (tid >= s) ? sm[tid - s] : 0;
    __syncthreads();
    sm[tid] += add;
    __syncthreads();
  }
  int excl = sm[tid] - d;
  if (node < NN) offs[node] = base + excl;
  if (node == NN - 1) offs[NN] = NE;
  ncur[tid] = base + excl;
  __syncthreads();
  for (int e = tid; e < cnt; e += 256) {
    unsigned int v = __builtin_nontemporal_load(&st[e]);
    int p = atomicAdd(&ncur[v >> 16], 1);
    csr_src[p] = (unsigned short)(v & 0xffffu);
  }
}

// h = bf16(emb[x]); BN stats for layer 0 on the ROUNDED values.
__global__ __launch_bounds__(256) void embed_stats_kernel(const int* __restrict__ x,
    const float* __restrict__ emb, unsigned short* __restrict__ hb, float* __restrict__ stats0) {
  int c = threadIdx.x & 63;
  int wave = (blockIdx.x * blockDim.x + threadIdx.x) >> 6;
  int nw = (gridDim.x * blockDim.x) >> 6;
  float ls = 0.f, lq = 0.f;
  for (int i = wave; i < NN; i += nw) {
    float v = emb[x[i] * CCH + c];
    unsigned int r = f2bf(v);
    hb[(size_t)i * CCH + c] = (unsigned short)r;
    float vr = bf2f(r);
    ls += vr; lq += vr * vr;
  }
  __shared__ float s1[256], s2[256];
  s1[threadIdx.x] = ls; s2[threadIdx.x] = lq;
  __syncthreads();
  if (threadIdx.x < 64) {
    float a = s1[threadIdx.x] + s1[threadIdx.x + 64] + s1[threadIdx.x + 128] + s1[threadIdx.x + 192];
    float b = s2[threadIdx.x] + s2[threadIdx.x + 64] + s2[threadIdx.x + 128] + s2[threadIdx.x + 192];
    atomicAdd(&stats0[c], a);
    atomicAdd(&stats0[64 + c], b);
  }
}

// Fused BN-fold + GEMM (round-16 VALU version), 64-node tile. h read NT
// (streaming; keep L2 for hwb slabs + aggregate's working set).
__global__ __launch_bounds__(256) void gemm_kernel(const unsigned short* __restrict__ hb,
    const float* __restrict__ W, const float* __restrict__ gamma,
    const float* __restrict__ beta, const float* __restrict__ stats,
    const float* __restrict__ dis, unsigned short* __restrict__ hwb) {
  __shared__ float Ws[64 * 64];
  __shared__ float HsT[64 * 67];   // [k][node], stride 67: 2-way bank alias (free)
  __shared__ float sm_a[64], sm_b2[64], sm_bias2[64];
  __shared__ float sm_part[4][64];
  int tid = threadIdx.x;
  if (tid < 64) {
    float inv_n = 1.0f / (float)NN;
    float m = stats[tid] * inv_n;
    float var = stats[64 + tid] * inv_n - m * m;
    float rstd = rsqrtf(var + BN_EPS);
    float av = gamma[tid] * rstd;
    sm_a[tid] = av;
    sm_b2[tid] = beta[tid] - m * av;
  }
  __syncthreads();
  int nodeBase = blockIdx.x * 64;
  for (int idx = tid; idx < 4096; idx += 256) Ws[idx] = sm_a[idx >> 6] * W[idx];
  const unsigned int* h32 = (const unsigned int*)hb;  // [N][32] channel pairs
  for (int idx = tid; idx < 2048; idx += 256) {       // 64 nodes x 32 pairs
    int node = idx >> 5, cp = idx & 31;
    int gn = nodeBase + node;
    unsigned int u = (gn < NN) ? __builtin_nontemporal_load(&h32[(size_t)gn * 32 + cp]) : 0u;
    HsT[(2 * cp) * 67 + node]     = bf2f(u & 0xffffu);
    HsT[(2 * cp + 1) * 67 + node] = bf2f(u >> 16);
  }
  {  // bias2[j] = sum_k b2[k]*W[k][j], k-split over 4 groups of 16
    int j = tid & 63, kg = tid >> 6;
    float s = 0.f;
#pragma unroll
    for (int k = kg * 16; k < kg * 16 + 16; ++k) s += sm_b2[k] * W[k * 64 + j];
    sm_part[kg][j] = s;
  }
  __syncthreads();
  if (tid < 64)
    sm_bias2[tid] = sm_part[0][tid] + sm_part[1][tid] + sm_part[2][tid] + sm_part[3][tid];
  __syncthreads();
  int tc = tid & 15;   // channels tc*4..+3
  int tr = tid >> 4;   // nodes tr*4..+3
  float4 bb = *(const float4*)&sm_bias2[tc * 4];
  float acc[4][4];
#pragma unroll
  for (int i = 0; i < 4; ++i) { acc[i][0] = bb.x; acc[i][1] = bb.y; acc[i][2] = bb.z; acc[i][3] = bb.w; }
#pragma unroll 4
  for (int k = 0; k < 64; ++k) {
    float4 wv = *(const float4*)&Ws[k * 64 + tc * 4];
    float4 h0 = *(const float4*)&HsT[k * 67 + tr * 4];
    float hv[4] = {h0.x, h0.y, h0.z, h0.w};
    float wl[4] = {wv.x, wv.y, wv.z, wv.w};
#pragma unroll
    for (int i = 0; i < 4; ++i)
#pragma unroll
      for (int j = 0; j < 4; ++j) acc[i][j] = fmaf(hv[i], wl[j], acc[i][j]);
  }
  unsigned short* slabp = hwb + (size_t)(tc >> 2) * NN * 16;
  int coff = (tc & 3) * 4;
#pragma unroll
  for (int i = 0; i < 4; ++i) {
    int gn = nodeBase + tr * 4 + i;
    if (gn < NN) {
      float dv = dis[gn];
      uint2 o;
      o.x = f2bf(acc[i][0] * dv) | (f2bf(acc[i][1] * dv) << 16);
      o.y = f2bf(acc[i][2] * dv) | (f2bf(acc[i][3] * dv) << 16);
      *(uint2*)&slabp[(size_t)gn * 16 + coff] = o;
    }
  }
}

// PULL aggregate (round-13/16 shape, best measured) + NT hints on the
// STREAMING accesses (csr_src, h) so they don't evict the L2-resident slab:
// per-XCD working set was slab 1.6MB + csr 2.4MB + h streams > 4MiB L2.
// Gather loads (slab) stay cached.
__global__ __launch_bounds__(256) void aggregate_kernel(unsigned int* __restrict__ h32,
    const unsigned short* __restrict__ hwb, const float* __restrict__ dis,
    const int* __restrict__ offs, const unsigned short* __restrict__ csr_src,
    const float* __restrict__ conv_b_l, float* __restrict__ stats_next) {
  int tid = threadIdx.x;
  int b = blockIdx.x;
  int slab = b & 3;                            // XCD = b&7; slab = XCD&3
  int subIdx = (b >> 3) * 2 + ((b >> 2) & 1);  // block index among those sharing slab
  int wid = subIdx * 4 + (tid >> 6);
  int nwSlab = (gridDim.x >> 2) * 4;           // waves per slab
  int chunk = (NN + nwSlab - 1) / nwSlab;
  int lo = wid * chunk;
  int hi = lo + chunk; if (hi > NN) hi = NN;
  int lane = tid & 63;
  int slot = lane >> 3;                        // which edge of the octet
  int l = lane & 7;                            // channel pair within slab (16 ch)
  int cbase = slab * 16;
  const unsigned short* slabp = hwb + (size_t)slab * NN * 16;
  float2 cb = ((const float2*)conv_b_l)[slab * 8 + l];
  float ls0 = 0.f, ls1 = 0.f, lq0 = 0.f, lq1 = 0.f;
  for (int i = lo; i < hi; ++i) {
    float a0 = 0.f, a1 = 0.f;
    if (slot == 0) {  // self term (pre-scaled by dis_i)
      unsigned int sv = *(const unsigned int*)&slabp[(size_t)i * 16 + 2 * l];
      a0 = bf2f(sv & 0xffffu); a1 = bf2f(sv >> 16);
    }
    int e0 = offs[i], e1 = offs[i + 1];
    for (int base = e0; base < e1; base += 32) {
      int iA = base + slot, iB = iA + 8, iC = iA + 16, iD = iA + 24;
      int okA = iA < e1, okB = iB < e1, okC = iC < e1, okD = iD < e1;
      int sA = __builtin_nontemporal_load(&csr_src[okA ? iA : e1 - 1]);
      int sB = __builtin_nontemporal_load(&csr_src[okB ? iB : e1 - 1]);
      int sC = __builtin_nontemporal_load(&csr_src[okC ? iC : e1 - 1]);
      int sD = __builtin_nontemporal_load(&csr_src[okD ? iD : e1 - 1]);
      unsigned int uA = *(const unsigned int*)&slabp[(size_t)sA * 16 + 2 * l];
      unsigned int uB = *(const unsigned int*)&slabp[(size_t)sB * 16 + 2 * l];
      unsigned int uC = *(const unsigned int*)&slabp[(size_t)sC * 16 + 2 * l];
      unsigned int uD = *(const unsigned int*)&slabp[(size_t)sD * 16 + 2 * l];
      uA = okA ? uA : 0u;
      uB = okB ? uB : 0u;
      uC = okC ? uC : 0u;
      uD = okD ? uD : 0u;
      a0 += bf2f(uA & 0xffffu) + bf2f(uB & 0xffffu) + bf2f(uC & 0xffffu) + bf2f(uD & 0xffffu);
      a1 += bf2f(uA >> 16) + bf2f(uB >> 16) + bf2f(uC >> 16) + bf2f(uD >> 16);
    }
    a0 += __shfl_xor(a0, 8); a0 += __shfl_xor(a0, 16); a0 += __shfl_xor(a0, 32);
    a1 += __shfl_xor(a1, 8); a1 += __shfl_xor(a1, 16); a1 += __shfl_xor(a1, 32);
    if (slot == 0) {
      unsigned int hu = __builtin_nontemporal_load(&h32[(size_t)i * 32 + slab * 8 + l]);
      float d = dis[i];
      float v0 = bf2f(hu & 0xffffu) + cb.x + d * a0;
      float v1 = bf2f(hu >> 16)     + cb.y + d * a1;
      v0 = v0 > 0.f ? v0 : 0.f;
      v1 = v1 > 0.f ? v1 : 0.f;
      unsigned int b0 = f2bf(v0), b1 = f2bf(v1);
      __builtin_nontemporal_store(b0 | (b1 << 16), &h32[(size_t)i * 32 + slab * 8 + l]);
      float r0 = bf2f(b0), r1 = bf2f(b1);
      ls0 += r0; lq0 += r0 * r0; ls1 += r1; lq1 += r1 * r1;
    }
  }
  __shared__ float2 s1[256], s2[256];
  float2 t1; t1.x = ls0; t1.y = ls1;
  float2 t2; t2.x = lq0; t2.y = lq1;
  s1[tid] = t1; s2[tid] = t2;
  __syncthreads();
  if (tid < 16) {  // this block covers 16 channels: cbase + tid
    int pair = tid >> 1, comp = tid & 1;   // slot-0 lanes 0..7 of each wave
    float a = 0.f, bb = 0.f;
#pragma unroll
    for (int w = 0; w < 4; ++w) {
      float2 u1 = s1[w * 64 + pair];
      float2 u2 = s2[w * 64 + pair];
      a += comp ? u1.y : u1.x;
      bb += comp ? u2.y : u2.x;
    }
    atomicAdd(&stats_next[cbase + tid], a);
    atomicAdd(&stats_next[64 + cbase + tid], bb);
  }
}

// batch is SORTED: chunked per-wave register accumulation. h read as bf16 (NT).
__global__ __launch_bounds__(256) void pool_kernel(const unsigned short* __restrict__ hb,
    const int* __restrict__ batch, float* __restrict__ pooled, float* __restrict__ counts) {
  int c = threadIdx.x & 63;
  int wid = (blockIdx.x * blockDim.x + threadIdx.x) >> 6;
  int nw = (gridDim.x * blockDim.x) >> 6;
  int chunk = (NN + nw - 1) / nw;
  int lo = wid * chunk;
  int hi = lo + chunk; if (hi > NN) hi = NN;
  if (lo >= hi) return;
  int g = batch[lo];
  float acc = 0.f, cnt = 0.f;
  for (int i = lo; i < hi; ++i) {
    int gi = batch[i];
    if (gi != g) {
      atomicAdd(&pooled[g * CCH + c], acc);
      if (c == 0) atomicAdd(&counts[g], cnt);
      g = gi; acc = 0.f; cnt = 0.f;
    }
    acc += bf2f((unsigned int)__builtin_nontemporal_load(&hb[(size_t)i * CCH + c]));
    cnt += 1.f;
  }
  atomicAdd(&pooled[g * CCH + c], acc);
  if (c == 0) atomicAdd(&counts[g], cnt);
}

__global__ __launch_bounds__(128) void mlp_kernel(const float* __restrict__ pooled,
    const float* __restrict__ counts, const float* __restrict__ hid_w,
    const float* __restrict__ hid_b, const float* __restrict__ out_w,
    const float* __restrict__ out_b, float* __restrict__ out) {
  int g = blockIdx.x;
  int t = threadIdx.x;  // 128 threads
  __shared__ float p[64], hid[128];
  if (t < 64) {
    float cnt = counts[g];
    cnt = cnt > 1.f ? cnt : 1.f;
    p[t] = pooled[g * CCH + t] / cnt;
  }
  __syncthreads();
  float acc = hid_b[t];
  for (int k = 0; k < 64; ++k) acc = fmaf(p[k], hid_w[k * HID + t], acc);
  acc = acc > 0.f ? acc : 0.f;
  hid[t] = acc;
  __syncthreads();
  if (t < 64) {
    float o = out_b[t];
    for (int j = 0; j < 128; ++j) o = fmaf(hid[j], out_w[j * CCH + t], o);
    out[g * CCH + t] = o;
  }
}

extern "C" void kernel_launch(void* const* d_in, const int* in_sizes, int n_in,
                              void* d_out, int out_size, void* d_ws, size_t ws_size,
                              hipStream_t stream) {
  const int* x       = (const int*)d_in[0];
  const int* ei      = (const int*)d_in[1];
  const int* batch   = (const int*)d_in[2];
  const float* emb   = (const float*)d_in[3];
  const float* gamma = (const float*)d_in[4];
  const float* beta  = (const float*)d_in[5];
  const float* convw = (const float*)d_in[6];
  const float* convb = (const float*)d_in[7];
  const float* hid_w = (const float*)d_in[8];
  const float* hid_b = (const float*)d_in[9];
  const float* out_w = (const float*)d_in[10];
  const float* out_b = (const float*)d_in[11];
  float* out = (float*)d_out;

  float* ws     = (float*)d_ws;
  float* stats  = ws + OFF_STATS;
  float* pooled = ws + OFF_POOLED;
  float* counts = ws + OFF_COUNTS;
  int*   gcur   = (int*)(ws + OFF_GCUR);
  float* dis    = ws + OFF_DIS;
  int*   offs   = (int*)(ws + OFF_OFFS);
  unsigned short* csrsrc = (unsigned short*)(ws + OFF_CSRSRC);
  unsigned short* hb  = (unsigned short*)(ws + OFF_H);
  unsigned int*   h32 = (unsigned int*)(ws + OFF_H);
  unsigned short* hwb = (unsigned short*)(ws + OFF_HW);
  unsigned int* staging = (unsigned int*)(ws + OFF_HW);  // aliases hwb (dead after bucket_build)

  hipMemsetAsync(ws, 0, MEMSET_F * sizeof(float), stream);
  bucket_scatter_kernel<<<(NE + EDGE_CHUNK - 1) / EDGE_CHUNK, 256, 0, stream>>>(ei, gcur, staging);
  bucket_build_kernel<<<SCAN_NB, 256, 0, stream>>>(staging, gcur, offs, dis, csrsrc);
  embed_stats_kernel<<<512, 256, 0, stream>>>(x, emb, hb, stats);

  for (int l = 0; l < NLAYER; ++l) {
    gemm_kernel<<<(NN + 63) / 64, 256, 0, stream>>>(hb, convw + l * 4096,
                                                    gamma + l * 64, beta + l * 64,
                                                    stats + l * 128, dis, hwb);
    aggregate_kernel<<<2048, 256, 0, stream>>>(h32, hwb, dis, offs, csrsrc,
                                               convb + l * 64, stats + (l + 1) * 128);
  }

  pool_kernel<<<128, 256, 0, stream>>>(hb, batch, pooled, counts);
  mlp_kernel<<<NG, 128, 0, stream>>>(pooled, counts, hid_w, hid_b, out_w, out_b, out);
}

// Round 21
// 719.106 us; speedup vs baseline: 1.3113x; 1.3113x over previous
//
#include <hip/hip_runtime.h>

#define NN 50000
#define NE 1200000
#define CCH 64
#define NLAYER 8
#define HID 128
#define NG 128
#define BN_EPS 1e-5f
#define SCAN_NB ((NN + 255) / 256)   // 196 buckets
#define EDGE_CHUNK 8192              // edges per bucket_scatter block
#define BCAP 8064                    // staging capacity per bucket (mean 6144, +24 sigma)

// ---- workspace layout (offsets in floats) ----
enum : size_t {
  OFF_STATS  = 0,
  OFF_POOLED = 1152,
  OFF_COUNTS = 9344,
  OFF_GCUR   = 9472,       // 196 bucket counters (ints)
  MEMSET_F   = 9728,
  OFF_DIS    = 9728,
  OFF_OFFS   = 59728,      // N+1 (+pad)
  OFF_CSRSRC = 109988,     // ushort[E]
  OFF_H      = 709988,     // ushort[N*64] bf16 (800000 floats)
  OFF_HW     = 2309988,    // ushort[4][N][16] bf16 slabs; staging (uint[196*BCAP]) aliases
  WS_FLOATS  = 3909988
};

__device__ __forceinline__ float bf2f(unsigned int hs) {
  union { unsigned int u; float f; } c; c.u = hs << 16; return c.f;
}
__device__ __forceinline__ unsigned int f2bf(float x) {
  union { float f; unsigned int u; } c; c.f = x;
  return (c.u + 0x7fffu + ((c.u >> 16) & 1u)) >> 16;  // RNE
}

// ---- CSR build phase A: bucket edges by dst>>8 into fixed-capacity staging.
__global__ __launch_bounds__(256) void bucket_scatter_kernel(const int* __restrict__ ei,
    int* __restrict__ gcur, unsigned int* __restrict__ staging) {
  __shared__ int bcnt[SCAN_NB];
  __shared__ int bbase[SCAN_NB];
  int tid = threadIdx.x;
  int lo = blockIdx.x * EDGE_CHUNK;
  int hi = lo + EDGE_CHUNK; if (hi > NE) hi = NE;
  for (int b = tid; b < SCAN_NB; b += 256) bcnt[b] = 0;
  __syncthreads();
  for (int e = lo + tid; e < hi; e += 256)
    atomicAdd(&bcnt[ei[NE + e] >> 8], 1);
  __syncthreads();
  for (int b = tid; b < SCAN_NB; b += 256) {
    int c = bcnt[b];
    bbase[b] = c ? (b * BCAP + atomicAdd(&gcur[b], c)) : 0;
    bcnt[b] = 0;
  }
  __syncthreads();
  for (int e = lo + tid; e < hi; e += 256) {
    int src = ei[e], dst = ei[NE + e];
    int b = dst >> 8;
    int p = bbase[b] + atomicAdd(&bcnt[b], 1);
    staging[p] = ((unsigned int)(dst & 255) << 16) | (unsigned int)src;
  }
}

// ---- CSR build phase B (scan fused): per bucket — block computes its own
// prefix over gcur, then LDS degree histogram -> dis, LDS scan -> offs,
// LDS cursors -> csr_src placement.
__global__ __launch_bounds__(256) void bucket_build_kernel(const unsigned int* __restrict__ staging,
    const int* __restrict__ gcur,
    int* __restrict__ offs, float* __restrict__ dis, unsigned short* __restrict__ csr_src) {
  __shared__ int hcnt[256];
  __shared__ int sm[256];
  __shared__ int ncur[256];
  __shared__ int sm_base;
  int b = blockIdx.x;
  int tid = threadIdx.x;
  int cnt = gcur[b];
  if (tid < 64) {
    int s = 0;
    for (int j = tid; j < b; j += 64) s += gcur[j];
    for (int d = 1; d < 64; d <<= 1) s += __shfl_xor(s, d);
    if (tid == 0) sm_base = s;
  }
  const unsigned int* st = staging + (size_t)b * BCAP;
  hcnt[tid] = 0;
  __syncthreads();
  int base = sm_base;
  for (int e = tid; e < cnt; e += 256)
    atomicAdd(&hcnt[st[e] >> 16], 1);
  __syncthreads();
  int d = hcnt[tid];
  int node = (b << 8) + tid;
  if (node < NN) dis[node] = rsqrtf((float)(d + 1));  // +1 self-loop
  sm[tid] = d;
  __syncthreads();
  for (int s = 1; s < 256; s <<= 1) {
    int add = (tid >= s) ? sm[tid - s] : 0;
    __syncthreads();
    sm[tid] += add;
    __syncthreads();
  }
  int excl = sm[tid] - d;
  if (node < NN) offs[node] = base + excl;
  if (node == NN - 1) offs[NN] = NE;
  ncur[tid] = base + excl;
  __syncthreads();
  for (int e = tid; e < cnt; e += 256) {
    unsigned int v = st[e];
    int p = atomicAdd(&ncur[v >> 16], 1);
    csr_src[p] = (unsigned short)(v & 0xffffu);
  }
}

// h = bf16(emb[x]); BN stats for layer 0 on the ROUNDED values.
__global__ __launch_bounds__(256) void embed_stats_kernel(const int* __restrict__ x,
    const float* __restrict__ emb, unsigned short* __restrict__ hb, float* __restrict__ stats0) {
  int c = threadIdx.x & 63;
  int wave = (blockIdx.x * blockDim.x + threadIdx.x) >> 6;
  int nw = (gridDim.x * blockDim.x) >> 6;
  float ls = 0.f, lq = 0.f;
  for (int i = wave; i < NN; i += nw) {
    float v = emb[x[i] * CCH + c];
    unsigned int r = f2bf(v);
    hb[(size_t)i * CCH + c] = (unsigned short)r;
    float vr = bf2f(r);
    ls += vr; lq += vr * vr;
  }
  __shared__ float s1[256], s2[256];
  s1[threadIdx.x] = ls; s2[threadIdx.x] = lq;
  __syncthreads();
  if (threadIdx.x < 64) {
    float a = s1[threadIdx.x] + s1[threadIdx.x + 64] + s1[threadIdx.x + 128] + s1[threadIdx.x + 192];
    float b = s2[threadIdx.x] + s2[threadIdx.x + 64] + s2[threadIdx.x + 128] + s2[threadIdx.x + 192];
    atomicAdd(&stats0[c], a);
    atomicAdd(&stats0[64 + c], b);
  }
}

// Fused BN-fold + GEMM (round-16 VALU version, best measured), 64-node tile.
__global__ __launch_bounds__(256) void gemm_kernel(const unsigned short* __restrict__ hb,
    const float* __restrict__ W, const float* __restrict__ gamma,
    const float* __restrict__ beta, const float* __restrict__ stats,
    const float* __restrict__ dis, unsigned short* __restrict__ hwb) {
  __shared__ float Ws[64 * 64];
  __shared__ float HsT[64 * 67];   // [k][node], stride 67: 2-way bank alias (free)
  __shared__ float sm_a[64], sm_b2[64], sm_bias2[64];
  __shared__ float sm_part[4][64];
  int tid = threadIdx.x;
  if (tid < 64) {
    float inv_n = 1.0f / (float)NN;
    float m = stats[tid] * inv_n;
    float var = stats[64 + tid] * inv_n - m * m;
    float rstd = rsqrtf(var + BN_EPS);
    float av = gamma[tid] * rstd;
    sm_a[tid] = av;
    sm_b2[tid] = beta[tid] - m * av;
  }
  __syncthreads();
  int nodeBase = blockIdx.x * 64;
  for (int idx = tid; idx < 4096; idx += 256) Ws[idx] = sm_a[idx >> 6] * W[idx];
  const unsigned int* h32 = (const unsigned int*)hb;  // [N][32] channel pairs
  for (int idx = tid; idx < 2048; idx += 256) {       // 64 nodes x 32 pairs
    int node = idx >> 5, cp = idx & 31;
    int gn = nodeBase + node;
    unsigned int u = (gn < NN) ? h32[(size_t)gn * 32 + cp] : 0u;
    HsT[(2 * cp) * 67 + node]     = bf2f(u & 0xffffu);
    HsT[(2 * cp + 1) * 67 + node] = bf2f(u >> 16);
  }
  {  // bias2[j] = sum_k b2[k]*W[k][j], k-split over 4 groups of 16
    int j = tid & 63, kg = tid >> 6;
    float s = 0.f;
#pragma unroll
    for (int k = kg * 16; k < kg * 16 + 16; ++k) s += sm_b2[k] * W[k * 64 + j];
    sm_part[kg][j] = s;
  }
  __syncthreads();
  if (tid < 64)
    sm_bias2[tid] = sm_part[0][tid] + sm_part[1][tid] + sm_part[2][tid] + sm_part[3][tid];
  __syncthreads();
  int tc = tid & 15;   // channels tc*4..+3
  int tr = tid >> 4;   // nodes tr*4..+3
  float4 bb = *(const float4*)&sm_bias2[tc * 4];
  float acc[4][4];
#pragma unroll
  for (int i = 0; i < 4; ++i) { acc[i][0] = bb.x; acc[i][1] = bb.y; acc[i][2] = bb.z; acc[i][3] = bb.w; }
#pragma unroll 4
  for (int k = 0; k < 64; ++k) {
    float4 wv = *(const float4*)&Ws[k * 64 + tc * 4];
    float4 h0 = *(const float4*)&HsT[k * 67 + tr * 4];
    float hv[4] = {h0.x, h0.y, h0.z, h0.w};
    float wl[4] = {wv.x, wv.y, wv.z, wv.w};
#pragma unroll
    for (int i = 0; i < 4; ++i)
#pragma unroll
      for (int j = 0; j < 4; ++j) acc[i][j] = fmaf(hv[i], wl[j], acc[i][j]);
  }
  unsigned short* slabp = hwb + (size_t)(tc >> 2) * NN * 16;
  int coff = (tc & 3) * 4;
#pragma unroll
  for (int i = 0; i < 4; ++i) {
    int gn = nodeBase + tr * 4 + i;
    if (gn < NN) {
      float dv = dis[gn];
      uint2 o;
      o.x = f2bf(acc[i][0] * dv) | (f2bf(acc[i][1] * dv) << 16);
      o.y = f2bf(acc[i][2] * dv) | (f2bf(acc[i][3] * dv) << 16);
      *(uint2*)&slabp[(size_t)gn * 16 + coff] = o;
    }
  }
}

// PULL aggregate (round-13/16 exact shape, best measured 60.7-61.6 us):
// 4-way channel-slab + XCD affinity, 8 lanes/edge (4B), 32 edges in flight
// (4 octets), 20 VGPR / 4KB LDS.
__global__ __launch_bounds__(256) void aggregate_kernel(unsigned int* __restrict__ h32,
    const unsigned short* __restrict__ hwb, const float* __restrict__ dis,
    const int* __restrict__ offs, const unsigned short* __restrict__ csr_src,
    const float* __restrict__ conv_b_l, float* __restrict__ stats_next) {
  int tid = threadIdx.x;
  int b = blockIdx.x;
  int slab = b & 3;                            // XCD = b&7; slab = XCD&3
  int subIdx = (b >> 3) * 2 + ((b >> 2) & 1);  // block index among those sharing slab
  int wid = subIdx * 4 + (tid >> 6);
  int nwSlab = (gridDim.x >> 2) * 4;           // waves per slab
  int chunk = (NN + nwSlab - 1) / nwSlab;
  int lo = wid * chunk;
  int hi = lo + chunk; if (hi > NN) hi = NN;
  int lane = tid & 63;
  int slot = lane >> 3;                        // which edge of the octet
  int l = lane & 7;                            // channel pair within slab (16 ch)
  int cbase = slab * 16;
  const unsigned short* slabp = hwb + (size_t)slab * NN * 16;
  float2 cb = ((const float2*)conv_b_l)[slab * 8 + l];
  float ls0 = 0.f, ls1 = 0.f, lq0 = 0.f, lq1 = 0.f;
  for (int i = lo; i < hi; ++i) {
    float a0 = 0.f, a1 = 0.f;
    if (slot == 0) {  // self term (pre-scaled by dis_i)
      unsigned int sv = *(const unsigned int*)&slabp[(size_t)i * 16 + 2 * l];
      a0 = bf2f(sv & 0xffffu); a1 = bf2f(sv >> 16);
    }
    int e0 = offs[i], e1 = offs[i + 1];
    for (int base = e0; base < e1; base += 32) {
      int iA = base + slot, iB = iA + 8, iC = iA + 16, iD = iA + 24;
      int okA = iA < e1, okB = iB < e1, okC = iC < e1, okD = iD < e1;
      int sA = csr_src[okA ? iA : e1 - 1];
      int sB = csr_src[okB ? iB : e1 - 1];
      int sC = csr_src[okC ? iC : e1 - 1];
      int sD = csr_src[okD ? iD : e1 - 1];
      unsigned int uA = *(const unsigned int*)&slabp[(size_t)sA * 16 + 2 * l];
      unsigned int uB = *(const unsigned int*)&slabp[(size_t)sB * 16 + 2 * l];
      unsigned int uC = *(const unsigned int*)&slabp[(size_t)sC * 16 + 2 * l];
      unsigned int uD = *(const unsigned int*)&slabp[(size_t)sD * 16 + 2 * l];
      uA = okA ? uA : 0u;
      uB = okB ? uB : 0u;
      uC = okC ? uC : 0u;
      uD = okD ? uD : 0u;
      a0 += bf2f(uA & 0xffffu) + bf2f(uB & 0xffffu) + bf2f(uC & 0xffffu) + bf2f(uD & 0xffffu);
      a1 += bf2f(uA >> 16) + bf2f(uB >> 16) + bf2f(uC >> 16) + bf2f(uD >> 16);
    }
    a0 += __shfl_xor(a0, 8); a0 += __shfl_xor(a0, 16); a0 += __shfl_xor(a0, 32);
    a1 += __shfl_xor(a1, 8); a1 += __shfl_xor(a1, 16); a1 += __shfl_xor(a1, 32);
    if (slot == 0) {
      unsigned int hu = h32[(size_t)i * 32 + slab * 8 + l];
      float d = dis[i];
      float v0 = bf2f(hu & 0xffffu) + cb.x + d * a0;
      float v1 = bf2f(hu >> 16)     + cb.y + d * a1;
      v0 = v0 > 0.f ? v0 : 0.f;
      v1 = v1 > 0.f ? v1 : 0.f;
      unsigned int b0 = f2bf(v0), b1 = f2bf(v1);
      h32[(size_t)i * 32 + slab * 8 + l] = b0 | (b1 << 16);
      float r0 = bf2f(b0), r1 = bf2f(b1);
      ls0 += r0; lq0 += r0 * r0; ls1 += r1; lq1 += r1 * r1;
    }
  }
  __shared__ float2 s1[256], s2[256];
  float2 t1; t1.x = ls0; t1.y = ls1;
  float2 t2; t2.x = lq0; t2.y = lq1;
  s1[tid] = t1; s2[tid] = t2;
  __syncthreads();
  if (tid < 16) {  // this block covers 16 channels: cbase + tid
    int pair = tid >> 1, comp = tid & 1;   // slot-0 lanes 0..7 of each wave
    float a = 0.f, bb = 0.f;
#pragma unroll
    for (int w = 0; w < 4; ++w) {
      float2 u1 = s1[w * 64 + pair];
      float2 u2 = s2[w * 64 + pair];
      a += comp ? u1.y : u1.x;
      bb += comp ? u2.y : u2.x;
    }
    atomicAdd(&stats_next[cbase + tid], a);
    atomicAdd(&stats_next[64 + cbase + tid], bb);
  }
}

// batch is SORTED: chunked per-wave register accumulation. h read as bf16.
__global__ __launch_bounds__(256) void pool_kernel(const unsigned short* __restrict__ hb,
    const int* __restrict__ batch, float* __restrict__ pooled, float* __restrict__ counts) {
  int c = threadIdx.x & 63;
  int wid = (blockIdx.x * blockDim.x + threadIdx.x) >> 6;
  int nw = (gridDim.x * blockDim.x) >> 6;
  int chunk = (NN + nw - 1) / nw;
  int lo = wid * chunk;
  int hi = lo + chunk; if (hi > NN) hi = NN;
  if (lo >= hi) return;
  int g = batch[lo];
  float acc = 0.f, cnt = 0.f;
  for (int i = lo; i < hi; ++i) {
    int gi = batch[i];
    if (gi != g) {
      atomicAdd(&pooled[g * CCH + c], acc);
      if (c == 0) atomicAdd(&counts[g], cnt);
      g = gi; acc = 0.f; cnt = 0.f;
    }
    acc += bf2f((unsigned int)hb[(size_t)i * CCH + c]);
    cnt += 1.f;
  }
  atomicAdd(&pooled[g * CCH + c], acc);
  if (c == 0) atomicAdd(&counts[g], cnt);
}

__global__ __launch_bounds__(128) void mlp_kernel(const float* __restrict__ pooled,
    const float* __restrict__ counts, const float* __restrict__ hid_w,
    const float* __restrict__ hid_b, const float* __restrict__ out_w,
    const float* __restrict__ out_b, float* __restrict__ out) {
  int g = blockIdx.x;
  int t = threadIdx.x;  // 128 threads
  __shared__ float p[64], hid[128];
  if (t < 64) {
    float cnt = counts[g];
    cnt = cnt > 1.f ? cnt : 1.f;
    p[t] = pooled[g * CCH + t] / cnt;
  }
  __syncthreads();
  float acc = hid_b[t];
  for (int k = 0; k < 64; ++k) acc = fmaf(p[k], hid_w[k * HID + t], acc);
  acc = acc > 0.f ? acc : 0.f;
  hid[t] = acc;
  __syncthreads();
  if (t < 64) {
    float o = out_b[t];
    for (int j = 0; j < 128; ++j) o = fmaf(hid[j], out_w[j * CCH + t], o);
    out[g * CCH + t] = o;
  }
}

extern "C" void kernel_launch(void* const* d_in, const int* in_sizes, int n_in,
                              void* d_out, int out_size, void* d_ws, size_t ws_size,
                              hipStream_t stream) {
  const int* x       = (const int*)d_in[0];
  const int* ei      = (const int*)d_in[1];
  const int* batch   = (const int*)d_in[2];
  const float* emb   = (const float*)d_in[3];
  const float* gamma = (const float*)d_in[4];
  const float* beta  = (const float*)d_in[5];
  const float* convw = (const float*)d_in[6];
  const float* convb = (const float*)d_in[7];
  const float* hid_w = (const float*)d_in[8];
  const float* hid_b = (const float*)d_in[9];
  const float* out_w = (const float*)d_in[10];
  const float* out_b = (const float*)d_in[11];
  float* out = (float*)d_out;

  float* ws     = (float*)d_ws;
  float* stats  = ws + OFF_STATS;
  float* pooled = ws + OFF_POOLED;
  float* counts = ws + OFF_COUNTS;
  int*   gcur   = (int*)(ws + OFF_GCUR);
  float* dis    = ws + OFF_DIS;
  int*   offs   = (int*)(ws + OFF_OFFS);
  unsigned short* csrsrc = (unsigned short*)(ws + OFF_CSRSRC);
  unsigned short* hb  = (unsigned short*)(ws + OFF_H);
  unsigned int*   h32 = (unsigned int*)(ws + OFF_H);
  unsigned short* hwb = (unsigned short*)(ws + OFF_HW);
  unsigned int* staging = (unsigned int*)(ws + OFF_HW);  // aliases hwb (dead after bucket_build)

  hipMemsetAsync(ws, 0, MEMSET_F * sizeof(float), stream);
  bucket_scatter_kernel<<<(NE + EDGE_CHUNK - 1) / EDGE_CHUNK, 256, 0, stream>>>(ei, gcur, staging);
  bucket_build_kernel<<<SCAN_NB, 256, 0, stream>>>(staging, gcur, offs, dis, csrsrc);
  embed_stats_kernel<<<512, 256, 0, stream>>>(x, emb, hb, stats);

  for (int l = 0; l < NLAYER; ++l) {
    gemm_kernel<<<(NN + 63) / 64, 256, 0, stream>>>(hb, convw + l * 4096,
                                                    gamma + l * 64, beta + l * 64,
                                                    stats + l * 128, dis, hwb);
    aggregate_kernel<<<2048, 256, 0, stream>>>(h32, hwb, dis, offs, csrsrc,
                                               convb + l * 64, stats + (l + 1) * 128);
  }

  pool_kernel<<<128, 256, 0, stream>>>(hb, batch, pooled, counts);
  mlp_kernel<<<NG, 128, 0, stream>>>(pooled, counts, hid_w, hid_b, out_w, out_b, out);
}